// Round 12
// baseline (1016.064 us; speedup 1.0000x reference)
//
#include <hip/hip_runtime.h>
#include <hip/hip_bf16.h>
#include <stdint.h>

#define BL    4096      // BATCH*SEQ
#define DM    768       // d_model
#define DI    1536      // d_inner
#define DS    16        // d_state
#define DCONV 4
#define DTR   48        // dt_rank
#define NL    2
#define SEQL  2048
#define BATCH 2
#define VOC   32000
#define NCH   32        // scan chunks
#define CT    64        // steps per chunk (SEQL/NCH)

typedef __bf16 bf16_t;
typedef __bf16 bf16x8 __attribute__((ext_vector_type(8)));
typedef __bf16 bf16x4 __attribute__((ext_vector_type(4)));
typedef float  f32x4  __attribute__((ext_vector_type(4)));

__device__ __forceinline__ float sigmoidf_(float x) { return 1.f / (1.f + __expf(-x)); }
__device__ __forceinline__ float softplus_(float x) {
  return (x > 20.f) ? x : log1pf(__expf(x));
}

// ------- embedding gather (f32 h + bf16 copy); also one-time dtl pad-zero -------
__global__ __launch_bounds__(256) void k_embed(const int* __restrict__ x,
                                               const float* __restrict__ emb,
                                               float* __restrict__ h,
                                               bf16_t* __restrict__ hb,
                                               bf16_t* __restrict__ dtl) {
  int row = blockIdx.x;
  if (row < 256) {   // zero dtl cols 48..63 for rows row*16..row*16+15 (once)
    int r = row * 16 + (threadIdx.x >> 4);
    dtl[r * 64 + 48 + (threadIdx.x & 15)] = (bf16_t)0.f;
  }
  int tok = x[row];
  const float* e = emb + (size_t)tok * DM;
  float* hr = h + (size_t)row * DM;
  bf16_t* hbr = hb + (size_t)row * DM;
  for (int c = threadIdx.x; c < DM; c += 256) {
    float v = e[c];
    hr[c] = v;
    hbr[c] = (bf16_t)v;
  }
}

// ------------- batched weight conversion: ALL weights f32->bf16 in one pass -------------
#define NV0 1179648L   // W_in  (2*3072*768)/4
#define NV1 589824L    // W_out (2*768*1536)/4
#define NV2 6144000L   // head  (32000*768)/4
#define NS3 393216L    // W_x padded elems 2*128*1536
#define NS4 196608L    // W_dt padded elems 2*1536*64
#define NVT (NV0 + NV1 + NV2)
#define NTOT (NVT + NS3 + NS4)

__global__ __launch_bounds__(256) void k_cvtw(const float* __restrict__ Win,
                                              const float* __restrict__ Wout,
                                              const float* __restrict__ Whead,
                                              const float* __restrict__ Wx,
                                              const float* __restrict__ Wdt,
                                              bf16_t* __restrict__ bin,
                                              bf16_t* __restrict__ bout,
                                              bf16_t* __restrict__ bhead,
                                              bf16_t* __restrict__ bx,
                                              bf16_t* __restrict__ bdt) {
  long i = (long)blockIdx.x * 256 + threadIdx.x;
  if (i >= NTOT) return;
  if (i < NVT) {
    const float* s; bf16_t* d; long j = i;
    if (i < NV0)            { s = Win;   d = bin; }
    else if (i < NV0 + NV1) { s = Wout;  d = bout;  j = i - NV0; }
    else                    { s = Whead; d = bhead; j = i - NV0 - NV1; }
    float4 v = ((const float4*)s)[j];
    bf16x4 o;
    o[0] = (bf16_t)v.x; o[1] = (bf16_t)v.y; o[2] = (bf16_t)v.z; o[3] = (bf16_t)v.w;
    ((bf16x4*)d)[j] = o;
  } else if (i < NVT + NS3) {
    long j = i - NVT;                       // [l][128][1536]
    int l = (int)(j / (128 * 1536));
    int rr = (int)((j / 1536) % 128);
    int c = (int)(j % 1536);
    bx[j] = (bf16_t)(rr < 80 ? Wx[((long)l * 80 + rr) * 1536 + c] : 0.f);
  } else {
    long j = i - NVT - NS3;                 // [l][1536][64]
    int l = (int)(j / (1536 * 64));
    int r = (int)((j / 64) % 1536);
    int c = (int)(j & 63);
    bdt[j] = (bf16_t)(c < DTR ? Wdt[((long)l * 1536 + r) * DTR + c] : 0.f);
  }
}

// ------------- causal dw-conv + bias + silu -> bf16 -------------
__global__ __launch_bounds__(256) void k_conv(const float* __restrict__ xz,
                                              const float* __restrict__ cw,
                                              const float* __restrict__ cb,
                                              bf16_t* __restrict__ ucb, long total) {
  long i = (long)blockIdx.x * 256 + threadIdx.x;
  if (i >= total) return;
  int d = (int)(i % DI);
  long row = i / DI;
  int l = (int)(row % SEQL);
  const float* w = cw + (size_t)d * DCONV;
  float s = cb[d];
#pragma unroll
  for (int j = 0; j < DCONV; j++) {
    int lj = l - (DCONV - 1) + j;
    if (lj >= 0) s += xz[(row - (DCONV - 1) + j) * (2 * DI) + d] * w[j];
  }
  float v = s * sigmoidf_(s);
  ucb[i] = (bf16_t)v;
}

// ------------- x_proj finisher: sum 4 K-slices, emit xdbl f32 + dt-input bf16 -------------
__global__ __launch_bounds__(256) void k_xfin(const float* __restrict__ xp,
                                              float* __restrict__ xdbl,
                                              bf16_t* __restrict__ dtl) {
  long i = (long)blockIdx.x * 256 + threadIdx.x;
  if (i >= (long)BL * 80) return;
  float s = xp[i] + xp[i + (long)BL * 80] + xp[i + 2L * BL * 80] + xp[i + 3L * BL * 80];
  xdbl[i] = s;
  int row = (int)(i / 80), col = (int)(i % 80);
  if (col < DTR) dtl[(long)row * 64 + col] = (bf16_t)s;
}

// ============ chunked selective scan (u and dt read as bf16) ============
__global__ __launch_bounds__(256) void k_scan1(const bf16_t* __restrict__ dt,
                                               const bf16_t* __restrict__ uc,
                                               const float* __restrict__ xdbl,
                                               const float* __restrict__ A_log,
                                               float* __restrict__ cA,
                                               float* __restrict__ cB) {
  int gi = blockIdx.x * 256 + threadIdx.x;
  int s = gi & 15;
  int rest = gi >> 4;          // [b][c][d]
  int d = rest % DI;
  int rest2 = rest / DI;
  int c = rest2 % NCH;
  int b = rest2 / NCH;
  float a = -__expf(A_log[d * DS + s]);
  long l0 = (long)c * CT;
  const bf16_t* dtp = dt + ((long)b * SEQL + l0) * DI + d;
  const bf16_t* ucp = uc + ((long)b * SEQL + l0) * DI + d;
  const float*  Bp  = xdbl + ((long)b * SEQL + l0) * 80 + DTR + s;
  float S = 0.f, hh = 0.f;
#pragma unroll 4
  for (int l = 0; l < CT; l++) {
    float dtv = (float)dtp[(long)l * DI];
    float uv  = (float)ucp[(long)l * DI];
    float Bv  = Bp[(long)l * 80];
    S += dtv;
    hh = __expf(dtv * a) * hh + (dtv * uv) * Bv;
  }
  cA[gi] = __expf(a * S);
  cB[gi] = hh;
}

__global__ __launch_bounds__(256) void k_scan2(const float* __restrict__ cA,
                                               const float* __restrict__ cB,
                                               float* __restrict__ hst) {
  int gj = blockIdx.x * 256 + threadIdx.x;   // [b][d][s]
  int ds_ = gj & (DI * DS - 1);
  int b = gj / (DI * DS);
  float h = 0.f;
#pragma unroll
  for (int c = 0; c < NCH; c++) {
    long idx = ((long)(b * NCH + c) * DI * DS) + ds_;
    hst[idx] = h;
    h = cA[idx] * h + cB[idx];
  }
}

// ---- pass 3 + skip + gate fused. o aliases uc (in-place y over u): each (l,d)
// element is read by all 16 lanes before the s==0 lane writes it.
__global__ __launch_bounds__(256) void k_scan3g(const bf16_t* __restrict__ dt,
                                                const bf16_t* uc,
                                                const float* __restrict__ xdbl,
                                                const float* __restrict__ A_log,
                                                const float* __restrict__ hst,
                                                const float* __restrict__ xz,
                                                const float* __restrict__ Dsk,
                                                bf16_t* o) {
  int gi = blockIdx.x * 256 + threadIdx.x;
  int s = gi & 15;
  int rest = gi >> 4;
  int d = rest % DI;
  int rest2 = rest / DI;
  int c = rest2 % NCH;
  int b = rest2 / NCH;
  float a = -__expf(A_log[d * DS + s]);
  float dval = Dsk[d];
  long l0 = (long)c * CT;
  const bf16_t* dtp = dt + ((long)b * SEQL + l0) * DI + d;
  const bf16_t* ucp = uc + ((long)b * SEQL + l0) * DI + d;
  const float*  Bp  = xdbl + ((long)b * SEQL + l0) * 80 + DTR + s;
  const float*  Cp  = Bp + DS;
  const float*  zp  = xz + ((long)b * SEQL + l0) * (2 * DI) + DI + d;
  bf16_t* yp = o + ((long)b * SEQL + l0) * DI + d;
  float h = hst[gi];
#pragma unroll 4
  for (int l = 0; l < CT; l++) {
    float dtv = (float)dtp[(long)l * DI];
    float uv  = (float)ucp[(long)l * DI];
    float Bv  = Bp[(long)l * 80];
    float Cv  = Cp[(long)l * 80];
    h = __expf(dtv * a) * h + (dtv * uv) * Bv;
    float y = h * Cv;
    y += __shfl_xor(y, 1);
    y += __shfl_xor(y, 2);
    y += __shfl_xor(y, 4);
    y += __shfl_xor(y, 8);
    if (s == 0) {
      float z = zp[(long)l * 2 * DI];
      float yy = (y + uv * dval) * z * sigmoidf_(z);
      yp[(long)l * DI] = (bf16_t)yy;
    }
  }
}

// ---------------- final LayerNorm, write bf16 A-operand ----------------
__global__ __launch_bounds__(256) void k_ln(const float* __restrict__ h,
                                            const float* __restrict__ g,
                                            const float* __restrict__ bta,
                                            bf16_t* __restrict__ o) {
  __shared__ float sm[4];
  int row = blockIdx.x;
  int t = threadIdx.x;
  const float* hr = h + (long)row * DM;
  float v0 = hr[t], v1 = hr[t + 256], v2 = hr[t + 512];
  float s = v0 + v1 + v2;
#pragma unroll
  for (int off = 32; off > 0; off >>= 1) s += __shfl_down(s, off);
  if ((t & 63) == 0) sm[t >> 6] = s;
  __syncthreads();
  float mu = (sm[0] + sm[1] + sm[2] + sm[3]) * (1.f / DM);
  __syncthreads();
  float d0 = v0 - mu, d1 = v1 - mu, d2 = v2 - mu;
  float q = d0 * d0 + d1 * d1 + d2 * d2;
#pragma unroll
  for (int off = 32; off > 0; off >>= 1) q += __shfl_down(q, off);
  if ((t & 63) == 0) sm[t >> 6] = q;
  __syncthreads();
  float var = (sm[0] + sm[1] + sm[2] + sm[3]) * (1.f / DM);
  float rs = rsqrtf(var + 1e-5f);
  bf16_t* orow = o + (long)row * DM;
  orow[t]       = (bf16_t)(d0 * rs * g[t]       + bta[t]);
  orow[t + 256] = (bf16_t)(d1 * rs * g[t + 256] + bta[t + 256]);
  orow[t + 512] = (bf16_t)(d2 * rs * g[t + 512] + bta[t + 512]);
}

__device__ __forceinline__ void stage16(const bf16_t* gp, bf16_t* lp) {
  __builtin_amdgcn_global_load_lds(
      (const __attribute__((address_space(1))) uint32_t*)gp,
      (__attribute__((address_space(3))) uint32_t*)lp, 16, 0, 0);
}

#define WAITV8()  asm volatile("s_waitcnt vmcnt(8)" ::: "memory")
#define WAITV4()  asm volatile("s_waitcnt vmcnt(4)" ::: "memory")
#define WAITV0()  asm volatile("s_waitcnt vmcnt(0)" ::: "memory")
#define BARRIER() do { __builtin_amdgcn_s_barrier();                            \
                       asm volatile("" ::: "memory"); } while (0)

// ====== 256^2 BK=32 TRIPLE-buffered GEMM, 2-tile-deep prefetch ======
// C(MxN) = A(MxK) * W(NxK)^T. M==4096 (16 m-tiles, m-inner), N%256==0, K%32==0,
// K/32>=2, grid%8==0. 512 thr, 8 waves 2x4, wave tile 128x64.
// WHY: R8's 1-tile lookahead puts loads ~1000cy ahead of their wait; R9's
// interleave put them only ~300cy ahead (the stall). Here tile kt+2's 4 loads
// issue at iter kt and are waited at iter kt+2 -- ~2 iterations (~2300cy) in
// flight >> 900cy HBM latency. vmcnt(8) mid-loop (8 newer loads keep flying),
// vmcnt(4)/vmcnt(0) only in the 2-iter tail. 3 x 32KB buffers = 96KB LDS.
// LDS layout: pair-row XOR (R10-verified conflict-free for 64B logical rows):
// logical (r,c16) -> rowp=r>>1, chunk=((r&1)*4+c16)^(rowp&7); staging decodes
// the inverse on the GLOBAL address (global_load_lds writes linearly).
// EPI: 0 plain full-line | 1 bias + nontemporal full-line

#define GLD256(ab, j, ktt, pp) do {                                             \
    int L_ = (j) * 512 + tid;            /* 0..1023 chunk index */              \
    int rowp_ = L_ >> 3;                 /* 0..127 */                           \
    int chs_ = L_ & 7;                                                          \
    int chl_ = chs_ ^ (rowp_ & 7);                                              \
    int r_ = rowp_ * 2 + (chl_ >> 2);                                           \
    size_t col_ = (size_t)(ktt) * 32 + (size_t)((chl_ & 3) * 8);                \
    const bf16_t* gp_ = (ab) ? (Wp + ((size_t)(n0 + r_)) * K + col_)            \
                             : (Ap + ((size_t)(m0 + r_)) * K + col_);           \
    bf16_t* lp_ = lds + ((((pp) * 2 + (ab)) * 128 + rowp_) * 64) + chs_ * 8;    \
    stage16(gp_, lp_);                                                          \
  } while (0)

#define STAGE256(pp, ktt) do {                                                  \
    GLD256(0, 0, ktt, pp); GLD256(0, 1, ktt, pp);                               \
    GLD256(1, 0, ktt, pp); GLD256(1, 1, ktt, pp);                               \
  } while (0)

// byte offset of an 8-elem (16B) fragment read: lane reads row_, k-group kq
#define FRAG_BYTE(ab, pp, row_)                                                 \
    ((((pp) * 2 + (ab)) * 128 + ((row_) >> 1)) * 128 +                          \
     (((((row_) & 1) * 4 + kq) ^ (((row_) >> 1) & 7)) * 16))

#define COMPUTE256(pp) do {                                                     \
    const char* lb_ = (const char*)lds;                                         \
    bf16x8 bfr_[4];                                                             \
    _Pragma("unroll") for (int f = 0; f < 4; ++f) {                             \
      int row_ = wn * 64 + f * 16 + fr;                                         \
      bfr_[f] = *(const bf16x8*)(lb_ + FRAG_BYTE(1, pp, row_));                 \
    }                                                                           \
    _Pragma("unroll") for (int fm = 0; fm < 8; ++fm) {                          \
      int row_ = wm * 128 + fm * 16 + fr;                                       \
      bf16x8 af_ = *(const bf16x8*)(lb_ + FRAG_BYTE(0, pp, row_));              \
      __builtin_amdgcn_s_setprio(1);                                            \
      _Pragma("unroll") for (int fn = 0; fn < 4; ++fn)                          \
        acc[fm][fn] = __builtin_amdgcn_mfma_f32_16x16x32_bf16(                  \
            af_, bfr_[fn], acc[fm][fn], 0, 0, 0);                               \
      __builtin_amdgcn_s_setprio(0);                                            \
    }                                                                           \
  } while (0)

template <int EPI>
__global__ __launch_bounds__(512, 1) void k_gemm256(const bf16_t* __restrict__ Ap,
                                                    const bf16_t* __restrict__ Wp,
                                                    float* __restrict__ C,
                                                    const float* __restrict__ bias,
                                                    int K, int ldc) {
  __shared__ bf16_t lds[3 * 2 * 128 * 64];   // 96 KiB: [buf3][A|B][128 rowp][64]
  const int tid = threadIdx.x;
  const int lane = tid & 63;
  const int wid = tid >> 6;
  const int wm = wid >> 2, wn = wid & 3;
  const int fr = lane & 15, kq = lane >> 4;

  // bijective XCD swizzle (grid % 8 == 0), then m-inner tile decode
  const int cpx = gridDim.x >> 3;
  const int wg = ((int)blockIdx.x & 7) * cpx + ((int)blockIdx.x >> 3);
  const long m0 = (long)(wg & 15) * 256;
  const long n0 = (long)(wg >> 4) * 256;

  f32x4 acc[8][4];
#pragma unroll
  for (int i = 0; i < 8; i++)
#pragma unroll
    for (int j = 0; j < 4; j++) acc[i][j] = (f32x4){0.f, 0.f, 0.f, 0.f};

  STAGE256(0, 0);
  STAGE256(1, 1);                       // 8 loads in flight (tiles 0,1)
  const int NT = K >> 5;
  int p = 0;
  for (int kt = 0; kt < NT; ++kt) {
    if (kt + 2 < NT) {
      int p2 = p + 2; if (p2 >= 3) p2 -= 3;
      STAGE256(p2, kt + 2);             // 12 in flight
      WAITV8();                         // drain tile kt's 4 (issued 2 iters ago)
    } else if (kt + 1 < NT) {
      WAITV4();
    } else {
      WAITV0();
    }
    BARRIER();                          // all waves' tile-kt loads landed
    COMPUTE256(p);
    BARRIER();                          // reads done before buf p is re-staged
    if (++p >= 3) p -= 3;
  }

  // ---- LDS-transposed epilogue: 1 KB/wave full-line f32x4 stores (260-pad) ----
  {
    float* lf = (float*)(void*)lds;
    const int q = lane >> 4;
    const int cc = lane & 15;
    float4 bias4 = {0.f, 0.f, 0.f, 0.f};
    if (EPI == 1) bias4 = *(const float4*)&bias[n0 + lane * 4];
#pragma unroll
    for (int pp = 0; pp < 4; ++pp) {
      __syncthreads();
      if (wm == (pp >> 1)) {
        const int mgb = (pp & 1) * 4;
#pragma unroll
        for (int m4 = 0; m4 < 4; ++m4)
#pragma unroll
          for (int n = 0; n < 4; ++n) {
            f32x4 v = acc[mgb + m4][n];
            float* dst = &lf[(m4 * 16 + q * 4) * 260 + wn * 64 + n * 16 + cc];
#pragma unroll
            for (int r = 0; r < 4; ++r) dst[r * 260] = v[r];
          }
      }
      __syncthreads();
      const long rowg0 = m0 + pp * 64;
#pragma unroll
      for (int it = 0; it < 8; ++it) {
        int row_loc = wid * 8 + it;
        f32x4 v = *(const f32x4*)&lf[row_loc * 260 + lane * 4];
        float* gp = &C[(rowg0 + row_loc) * (long)ldc + n0 + lane * 4];
        if (EPI == 1) {
          v[0] += bias4.x; v[1] += bias4.y; v[2] += bias4.z; v[3] += bias4.w;
          __builtin_nontemporal_store(v, (f32x4*)gp);
        } else {
          *(f32x4*)gp = v;
        }
      }
    }
  }
}

// ====== 128^2 BK=64 double-buffered GEMM, 2 blocks/CU (unchanged, R8-proven) ======
// EPI: 4 softplus(acc+bias)->bf16 side | 5 += C + bf16 side | 7 K-slice partial
#define WAITV8B() asm volatile("s_waitcnt vmcnt(8)" ::: "memory")

#define GLD128(ab, j, ktt, pp) do {                                             \
    int idx_ = (j) * 256 + tid;                                                 \
    int r_ = idx_ >> 3; int c16_ = idx_ & 7;                                    \
    size_t col_ = kb + (size_t)(ktt) * 64 + (size_t)((c16_ ^ (r_ & 7)) << 3);   \
    const bf16_t* gp_ = (ab) ? (Wp + ((size_t)(n0 + r_)) * K + col_)            \
                             : (Ap + ((size_t)(m0 + r_)) * K + col_);           \
    bf16_t* lp_ = lds + ((((pp) * 2 + (ab)) * 128 + r_) * 64) + c16_ * 8;       \
    stage16(gp_, lp_);                                                          \
  } while (0)

#define STAGE128(pp, ktt) do {                                                  \
    GLD128(0, 0, ktt, pp); GLD128(0, 1, ktt, pp);                               \
    GLD128(0, 2, ktt, pp); GLD128(0, 3, ktt, pp);                               \
    GLD128(1, 0, ktt, pp); GLD128(1, 1, ktt, pp);                               \
    GLD128(1, 2, ktt, pp); GLD128(1, 3, ktt, pp);                               \
  } while (0)

#define COMPUTE128(pp, kh) do {                                                 \
    const char* lb_ = (const char*)lds;                                         \
    bf16x8 af_[4], bv_[4];                                                      \
    _Pragma("unroll") for (int f = 0; f < 4; ++f) {                             \
      int row_ = wn * 64 + f * 16 + fr;                                         \
      int byte_ = (((pp) * 2 + 1) * 128 + row_) * 128 +                         \
                  (((kh) * 64 + kq * 16) ^ ((row_ & 7) << 4));                  \
      bv_[f] = *(const bf16x8*)(lb_ + byte_);                                   \
    }                                                                           \
    _Pragma("unroll") for (int f = 0; f < 4; ++f) {                             \
      int row_ = wm * 64 + f * 16 + fr;                                         \
      int byte_ = (((pp) * 2 + 0) * 128 + row_) * 128 +                         \
                  (((kh) * 64 + kq * 16) ^ ((row_ & 7) << 4));                  \
      af_[f] = *(const bf16x8*)(lb_ + byte_);                                   \
    }                                                                           \
    __builtin_amdgcn_s_setprio(1);                                              \
    _Pragma("unroll") for (int fm = 0; fm < 4; ++fm)                            \
      _Pragma("unroll") for (int fn = 0; fn < 4; ++fn)                          \
        acc[fm][fn] = __builtin_amdgcn_mfma_f32_16x16x32_bf16(                  \
            af_[fm], bv_[fn], acc[fm][fn], 0, 0, 0);                            \
    __builtin_amdgcn_s_setprio(0);                                              \
  } while (0)

template <int EPI>
__global__ __launch_bounds__(256, 2) void k_gemm128(const bf16_t* __restrict__ Ap,
                                                    const bf16_t* __restrict__ Wp,
                                                    float* __restrict__ C,
                                                    const float* __restrict__ bias,
                                                    bf16_t* __restrict__ side,
                                                    int K, int Ksl, int ldc) {
  __shared__ bf16_t lds[2 * 2 * 128 * 64];   // 64 KiB
  const int tid = threadIdx.x;
  const int lane = tid & 63;
  const int wv = tid >> 6;
  const int wm = wv >> 1, wn = wv & 1;
  const int fr = lane & 15, kq = lane >> 4;
  const size_t kb = (size_t)blockIdx.y * Ksl;

  const int cpx = gridDim.x >> 3;
  const int wg = ((int)blockIdx.x & 7) * cpx + ((int)blockIdx.x >> 3);
  const long m0 = (long)(wg & 31) * 128;
  const long n0 = (long)(wg >> 5) * 128;

  f32x4 acc[4][4];
#pragma unroll
  for (int i = 0; i < 4; i++)
#pragma unroll
    for (int j = 0; j < 4; j++) acc[i][j] = (f32x4){0.f, 0.f, 0.f, 0.f};

  STAGE128(0, 0);
  const int NT = Ksl >> 6;
  for (int kt = 0; kt < NT; ++kt) {
    const int p = kt & 1;
    const bool pre = (kt + 1 < NT);
    if (pre) STAGE128(p ^ 1, kt + 1);
    if (pre) WAITV8B(); else WAITV0();
    BARRIER();
    COMPUTE128(p, 0);
    COMPUTE128(p, 1);
    BARRIER();
  }

  if (EPI == 7) {
    // K-slice partial: scattered f32 stores into per-slice scratch (tiny output)
    float* Cs = C + (size_t)blockIdx.y * (size_t)BL * 80;
    const int r4 = (lane >> 4) * 4;
    const int cc = lane & 15;
#pragma unroll
    for (int fm = 0; fm < 4; fm++) {
      long rowb = m0 + wm * 64 + fm * 16 + r4;
#pragma unroll
      for (int fn = 0; fn < 4; fn++) {
        long col = n0 + wn * 64 + fn * 16 + cc;
        if (col < 80) {
#pragma unroll
          for (int r = 0; r < 4; r++)
            Cs[(rowb + r) * 80 + col] = acc[fm][fn][r];
        }
      }
    }
    return;
  }

  // ---- full-line epilogue: 32-row chunks in LDS (132-f32 pad) ----
  {
    float* lf = (float*)(void*)lds;    // 32 x 132 f32 = 16.9 KB
    const int q = lane >> 4;
    const int cc = lane & 15;
    const int colt = (tid & 31) * 4;
    float4 bias4 = {0.f, 0.f, 0.f, 0.f};
    if (EPI == 4) bias4 = *(const float4*)&bias[n0 + colt];
#pragma unroll
    for (int p = 0; p < 4; ++p) {
      __syncthreads();
      if (wm == (p >> 1)) {
#pragma unroll
        for (int fl = 0; fl < 2; ++fl) {
          int fm = (p & 1) * 2 + fl;
#pragma unroll
          for (int fn = 0; fn < 4; ++fn) {
            f32x4 v = acc[fm][fn];
            float* dst = &lf[(fl * 16 + q * 4) * 132 + wn * 64 + fn * 16 + cc];
#pragma unroll
            for (int r = 0; r < 4; ++r) dst[r * 132] = v[r];
          }
        }
      }
      __syncthreads();
      const long rowg0 = m0 + p * 32;
#pragma unroll
      for (int it = 0; it < 4; ++it) {
        int rl = it * 8 + (tid >> 5);
        f32x4 v = *(const f32x4*)&lf[rl * 132 + colt];
        long row = rowg0 + rl;
        long cg = n0 + colt;
        if (EPI == 4) {
          bf16x4 s4;
          s4[0] = (bf16_t)softplus_(v[0] + bias4.x);
          s4[1] = (bf16_t)softplus_(v[1] + bias4.y);
          s4[2] = (bf16_t)softplus_(v[2] + bias4.z);
          s4[3] = (bf16_t)softplus_(v[3] + bias4.w);
          *(bf16x4*)&side[row * (long)ldc + cg] = s4;
        } else {  // EPI == 5: residual + bf16 side copy
          float* gp = &C[row * (long)ldc + cg];
          f32x4 c0 = *(const f32x4*)gp;
          v[0] += c0[0]; v[1] += c0[1]; v[2] += c0[2]; v[3] += c0[3];
          *(f32x4*)gp = v;
          bf16x4 s4;
          s4[0] = (bf16_t)v[0]; s4[1] = (bf16_t)v[1];
          s4[2] = (bf16_t)v[2]; s4[3] = (bf16_t)v[3];
          *(bf16x4*)&side[row * (long)ldc + cg] = s4;
        }
      }
    }
  }
}

static inline int cdiv_l(long a, long b) { return (int)((a + b - 1) / b); }

extern "C" void kernel_launch(void* const* d_in, const int* in_sizes, int n_in,
                              void* d_out, int out_size, void* d_ws, size_t ws_size,
                              hipStream_t stream) {
  (void)in_sizes; (void)n_in; (void)out_size; (void)ws_size;
  const int*   x      = (const int*)  d_in[0];
  const float* emb    = (const float*)d_in[1];
  const float* W_in   = (const float*)d_in[2];
  const float* conv_w = (const float*)d_in[3];
  const float* conv_b = (const float*)d_in[4];
  const float* W_x    = (const float*)d_in[5];
  const float* W_dt   = (const float*)d_in[6];
  const float* b_dt   = (const float*)d_in[7];
  const float* A_log  = (const float*)d_in[8];
  const float* D_skip = (const float*)d_in[9];
  const float* W_out  = (const float*)d_in[10];
  const float* ln_g   = (const float*)d_in[11];
  const float* ln_b   = (const float*)d_in[12];
  const float* head_w = (const float*)d_in[13];
  const float* head_b = (const float*)d_in[14];
  float* out = (float*)d_out;

  // bf16 staging in d_ws (~84 MB)
  bf16_t* abuf   = (bf16_t*)d_ws;                       // BL*DI (u, then y in-place)
  bf16_t* hbf    = abuf   + (size_t)BL * DI;            // BL*DM
  bf16_t* dtl    = hbf    + (size_t)BL * DM;            // BL*64
  bf16_t* wb_in  = dtl    + (size_t)BL * 64;            // 2*3072*768
  bf16_t* wb_out = wb_in  + (size_t)2 * 3072 * 768;     // 2*768*1536
  bf16_t* wb_hd  = wb_out + (size_t)2 * 768 * 1536;     // 32000*768
  bf16_t* wb_x   = wb_hd  + (size_t)VOC * DM;           // 2*128*1536
  bf16_t* wb_dt  = wb_x   + (size_t)2 * 128 * 1536;     // 2*1536*64

  // f32/bf16 intermediates overlaid into d_out (all dead before head GEMM)
  float*  xz    = out;
  float*  xdbl  = xz    + (size_t)BL * 2 * DI;
  float*  dtb_f = xdbl  + (size_t)BL * 80;              // region reused as bf16
  bf16_t* dtbb  = (bf16_t*)dtb_f;                       // BL*DI bf16
  float*  h     = dtb_f + (size_t)BL * DI;
  float*  cA    = h     + (size_t)BL * DM;
  float*  cB    = cA    + (size_t)BATCH * NCH * DI * DS;
  float*  hst   = cB    + (size_t)BATCH * NCH * DI * DS;
  float*  xpart = hst   + (size_t)BATCH * DI * DS;      // 4 * BL * 80

  const int scan_blocks = BATCH * NCH * DI * DS / 256;  // 6144
  const int st_blocks   = BATCH * DI * DS / 256;        // 192

  // all weight conversions in one pass (independent of activations)
  k_cvtw<<<cdiv_l(NTOT, 256), 256, 0, stream>>>(W_in, W_out, head_w, W_x, W_dt,
                                                wb_in, wb_out, wb_hd, wb_x, wb_dt);
  k_embed<<<BL, 256, 0, stream>>>(x, emb, h, hbf, dtl);

  for (int l = 0; l < NL; ++l) {
    // ---- in_proj: xz = h @ W_in^T  (4096 x 3072, K=768): 256^2 3-buf BK=32 ----
    k_gemm256<0><<<(BL / 256) * (2 * DI / 256), 512, 0, stream>>>(
        hbf, wb_in + (size_t)l * 3072 * 768, xz, nullptr, DM, 2 * DI);
    // ---- causal dw-conv + silu -> bf16 u (abuf) ----
    k_conv<<<cdiv_l((long)BL * DI, 256), 256, 0, stream>>>(
        xz, conv_w + (size_t)l * DI * DCONV, conv_b + (size_t)l * DI,
        abuf, (long)BL * DI);
    // ---- x_proj: 4 K-slice partials (no atomics) then finisher ----
    k_gemm128<7><<<dim3(32, 4), 256, 0, stream>>>(
        abuf, wb_x + (size_t)l * 128 * 1536, xpart, nullptr, nullptr,
        DI, DI / 4, 80);
    k_xfin<<<cdiv_l((long)BL * 80, 256), 256, 0, stream>>>(xpart, xdbl, dtl);
    // ---- dt = softplus(dtlin @ W_dt^T + b_dt) -> bf16 (K=64, NT=1) ----
    k_gemm128<4><<<(BL / 128) * (DI / 128), 256, 0, stream>>>(
        dtl, wb_dt + (size_t)l * 1536 * 64, nullptr, b_dt + (size_t)l * DI, dtbb,
        64, 64, DI);
    // ---- chunked selective scan (pass 3 fused with skip+gate, y in-place) ----
    k_scan1<<<scan_blocks, 256, 0, stream>>>(dtbb, abuf, xdbl,
                                             A_log + (size_t)l * DI * DS, cA, cB);
    k_scan2<<<st_blocks, 256, 0, stream>>>(cA, cB, hst);
    k_scan3g<<<scan_blocks, 256, 0, stream>>>(dtbb, abuf, xdbl,
                                              A_log + (size_t)l * DI * DS, hst,
                                              xz, D_skip + (size_t)l * DI, abuf);
    // ---- out_proj + residual: h += y @ W_out^T (K=1536) ----
    k_gemm128<5><<<(BL / 128) * (DM / 128), 256, 0, stream>>>(
        abuf, wb_out + (size_t)l * 768 * 1536, h, nullptr, hbf, DI, DI, DM);
  }

  // ---- final LN -> bf16, head GEMM + bias: 256^2 3-buf BK=32, nt full-line ----
  k_ln<<<BL, 256, 0, stream>>>(h, ln_g, ln_b, abuf);
  k_gemm256<1><<<(BL / 256) * (VOC / 256), 512, 0, stream>>>(
      abuf, wb_hd, out, head_b, DM, VOC);
}

// Round 13
// 953.113 us; speedup vs baseline: 1.0660x; 1.0660x over previous
//
#include <hip/hip_runtime.h>
#include <hip/hip_bf16.h>
#include <stdint.h>

#define BL    4096      // BATCH*SEQ
#define DM    768       // d_model
#define DI    1536      // d_inner
#define DS    16        // d_state
#define DCONV 4
#define DTR   48        // dt_rank
#define NL    2
#define SEQL  2048
#define BATCH 2
#define VOC   32000
#define NCH   32        // scan chunks
#define CT    64        // steps per chunk (SEQL/NCH)

typedef __bf16 bf16_t;
typedef __bf16 bf16x8 __attribute__((ext_vector_type(8)));
typedef __bf16 bf16x4 __attribute__((ext_vector_type(4)));
typedef float  f32x4  __attribute__((ext_vector_type(4)));

__device__ __forceinline__ float sigmoidf_(float x) { return 1.f / (1.f + __expf(-x)); }
__device__ __forceinline__ float softplus_(float x) {
  return (x > 20.f) ? x : log1pf(__expf(x));
}

// ------- embedding gather (f32 h + bf16 copy); also one-time dtl pad-zero -------
__global__ __launch_bounds__(256) void k_embed(const int* __restrict__ x,
                                               const float* __restrict__ emb,
                                               float* __restrict__ h,
                                               bf16_t* __restrict__ hb,
                                               bf16_t* __restrict__ dtl) {
  int row = blockIdx.x;
  if (row < 256) {   // zero dtl cols 48..63 for rows row*16..row*16+15 (once)
    int r = row * 16 + (threadIdx.x >> 4);
    dtl[r * 64 + 48 + (threadIdx.x & 15)] = (bf16_t)0.f;
  }
  int tok = x[row];
  const float* e = emb + (size_t)tok * DM;
  float* hr = h + (size_t)row * DM;
  bf16_t* hbr = hb + (size_t)row * DM;
  for (int c = threadIdx.x; c < DM; c += 256) {
    float v = e[c];
    hr[c] = v;
    hbr[c] = (bf16_t)v;
  }
}

// ------------- batched weight conversion: ALL weights f32->bf16 in one pass -------------
#define NV0 1179648L   // W_in  (2*3072*768)/4
#define NV1 589824L    // W_out (2*768*1536)/4
#define NV2 6144000L   // head  (32000*768)/4
#define NS3 393216L    // W_x padded elems 2*128*1536
#define NS4 196608L    // W_dt padded elems 2*1536*64
#define NVT (NV0 + NV1 + NV2)
#define NTOT (NVT + NS3 + NS4)

__global__ __launch_bounds__(256) void k_cvtw(const float* __restrict__ Win,
                                              const float* __restrict__ Wout,
                                              const float* __restrict__ Whead,
                                              const float* __restrict__ Wx,
                                              const float* __restrict__ Wdt,
                                              bf16_t* __restrict__ bin,
                                              bf16_t* __restrict__ bout,
                                              bf16_t* __restrict__ bhead,
                                              bf16_t* __restrict__ bx,
                                              bf16_t* __restrict__ bdt) {
  long i = (long)blockIdx.x * 256 + threadIdx.x;
  if (i >= NTOT) return;
  if (i < NVT) {
    const float* s; bf16_t* d; long j = i;
    if (i < NV0)            { s = Win;   d = bin; }
    else if (i < NV0 + NV1) { s = Wout;  d = bout;  j = i - NV0; }
    else                    { s = Whead; d = bhead; j = i - NV0 - NV1; }
    float4 v = ((const float4*)s)[j];
    bf16x4 o;
    o[0] = (bf16_t)v.x; o[1] = (bf16_t)v.y; o[2] = (bf16_t)v.z; o[3] = (bf16_t)v.w;
    ((bf16x4*)d)[j] = o;
  } else if (i < NVT + NS3) {
    long j = i - NVT;                       // [l][128][1536]
    int l = (int)(j / (128 * 1536));
    int rr = (int)((j / 1536) % 128);
    int c = (int)(j % 1536);
    bx[j] = (bf16_t)(rr < 80 ? Wx[((long)l * 80 + rr) * 1536 + c] : 0.f);
  } else {
    long j = i - NVT - NS3;                 // [l][1536][64]
    int l = (int)(j / (1536 * 64));
    int r = (int)((j / 64) % 1536);
    int c = (int)(j & 63);
    bdt[j] = (bf16_t)(c < DTR ? Wdt[((long)l * 1536 + r) * DTR + c] : 0.f);
  }
}

// ------------- causal dw-conv + bias + silu -> bf16 (xz now bf16) -------------
__global__ __launch_bounds__(256) void k_conv(const bf16_t* __restrict__ xz,
                                              const float* __restrict__ cw,
                                              const float* __restrict__ cb,
                                              bf16_t* __restrict__ ucb, long total) {
  long i = (long)blockIdx.x * 256 + threadIdx.x;
  if (i >= total) return;
  int d = (int)(i % DI);
  long row = i / DI;
  int l = (int)(row % SEQL);
  const float* w = cw + (size_t)d * DCONV;
  float s = cb[d];
#pragma unroll
  for (int j = 0; j < DCONV; j++) {
    int lj = l - (DCONV - 1) + j;
    if (lj >= 0) s += (float)xz[(row - (DCONV - 1) + j) * (2 * DI) + d] * w[j];
  }
  float v = s * sigmoidf_(s);
  ucb[i] = (bf16_t)v;
}

// ------------- x_proj finisher: sum 4 K-slices, emit xdbl f32 + dt-input bf16 -------------
__global__ __launch_bounds__(256) void k_xfin(const float* __restrict__ xp,
                                              float* __restrict__ xdbl,
                                              bf16_t* __restrict__ dtl) {
  long i = (long)blockIdx.x * 256 + threadIdx.x;
  if (i >= (long)BL * 80) return;
  float s = xp[i] + xp[i + (long)BL * 80] + xp[i + 2L * BL * 80] + xp[i + 3L * BL * 80];
  xdbl[i] = s;
  int row = (int)(i / 80), col = (int)(i % 80);
  if (col < DTR) dtl[(long)row * 64 + col] = (bf16_t)s;
}

// ============ chunked selective scan (u and dt read as bf16) ============
__global__ __launch_bounds__(256) void k_scan1(const bf16_t* __restrict__ dt,
                                               const bf16_t* __restrict__ uc,
                                               const float* __restrict__ xdbl,
                                               const float* __restrict__ A_log,
                                               float* __restrict__ cA,
                                               float* __restrict__ cB) {
  int gi = blockIdx.x * 256 + threadIdx.x;
  int s = gi & 15;
  int rest = gi >> 4;          // [b][c][d]
  int d = rest % DI;
  int rest2 = rest / DI;
  int c = rest2 % NCH;
  int b = rest2 / NCH;
  float a = -__expf(A_log[d * DS + s]);
  long l0 = (long)c * CT;
  const bf16_t* dtp = dt + ((long)b * SEQL + l0) * DI + d;
  const bf16_t* ucp = uc + ((long)b * SEQL + l0) * DI + d;
  const float*  Bp  = xdbl + ((long)b * SEQL + l0) * 80 + DTR + s;
  float S = 0.f, hh = 0.f;
#pragma unroll 4
  for (int l = 0; l < CT; l++) {
    float dtv = (float)dtp[(long)l * DI];
    float uv  = (float)ucp[(long)l * DI];
    float Bv  = Bp[(long)l * 80];
    S += dtv;
    hh = __expf(dtv * a) * hh + (dtv * uv) * Bv;
  }
  cA[gi] = __expf(a * S);
  cB[gi] = hh;
}

__global__ __launch_bounds__(256) void k_scan2(const float* __restrict__ cA,
                                               const float* __restrict__ cB,
                                               float* __restrict__ hst) {
  int gj = blockIdx.x * 256 + threadIdx.x;   // [b][d][s]
  int ds_ = gj & (DI * DS - 1);
  int b = gj / (DI * DS);
  float h = 0.f;
#pragma unroll
  for (int c = 0; c < NCH; c++) {
    long idx = ((long)(b * NCH + c) * DI * DS) + ds_;
    hst[idx] = h;
    h = cA[idx] * h + cB[idx];
  }
}

// ---- pass 3 + skip + gate fused. o aliases uc (in-place y over u): each (l,d)
// element is read by all 16 lanes before the s==0 lane writes it.
__global__ __launch_bounds__(256) void k_scan3g(const bf16_t* __restrict__ dt,
                                                const bf16_t* uc,
                                                const float* __restrict__ xdbl,
                                                const float* __restrict__ A_log,
                                                const float* __restrict__ hst,
                                                const bf16_t* __restrict__ xz,
                                                const float* __restrict__ Dsk,
                                                bf16_t* o) {
  int gi = blockIdx.x * 256 + threadIdx.x;
  int s = gi & 15;
  int rest = gi >> 4;
  int d = rest % DI;
  int rest2 = rest / DI;
  int c = rest2 % NCH;
  int b = rest2 / NCH;
  float a = -__expf(A_log[d * DS + s]);
  float dval = Dsk[d];
  long l0 = (long)c * CT;
  const bf16_t* dtp = dt + ((long)b * SEQL + l0) * DI + d;
  const bf16_t* ucp = uc + ((long)b * SEQL + l0) * DI + d;
  const float*  Bp  = xdbl + ((long)b * SEQL + l0) * 80 + DTR + s;
  const float*  Cp  = Bp + DS;
  const bf16_t* zp  = xz + ((long)b * SEQL + l0) * (2 * DI) + DI + d;
  bf16_t* yp = o + ((long)b * SEQL + l0) * DI + d;
  float h = hst[gi];
#pragma unroll 4
  for (int l = 0; l < CT; l++) {
    float dtv = (float)dtp[(long)l * DI];
    float uv  = (float)ucp[(long)l * DI];
    float Bv  = Bp[(long)l * 80];
    float Cv  = Cp[(long)l * 80];
    h = __expf(dtv * a) * h + (dtv * uv) * Bv;
    float y = h * Cv;
    y += __shfl_xor(y, 1);
    y += __shfl_xor(y, 2);
    y += __shfl_xor(y, 4);
    y += __shfl_xor(y, 8);
    if (s == 0) {
      float z = (float)zp[(long)l * 2 * DI];
      float yy = (y + uv * dval) * z * sigmoidf_(z);
      yp[(long)l * DI] = (bf16_t)yy;
    }
  }
}

// ---------------- final LayerNorm, write bf16 A-operand ----------------
__global__ __launch_bounds__(256) void k_ln(const float* __restrict__ h,
                                            const float* __restrict__ g,
                                            const float* __restrict__ bta,
                                            bf16_t* __restrict__ o) {
  __shared__ float sm[4];
  int row = blockIdx.x;
  int t = threadIdx.x;
  const float* hr = h + (long)row * DM;
  float v0 = hr[t], v1 = hr[t + 256], v2 = hr[t + 512];
  float s = v0 + v1 + v2;
#pragma unroll
  for (int off = 32; off > 0; off >>= 1) s += __shfl_down(s, off);
  if ((t & 63) == 0) sm[t >> 6] = s;
  __syncthreads();
  float mu = (sm[0] + sm[1] + sm[2] + sm[3]) * (1.f / DM);
  __syncthreads();
  float d0 = v0 - mu, d1 = v1 - mu, d2 = v2 - mu;
  float q = d0 * d0 + d1 * d1 + d2 * d2;
#pragma unroll
  for (int off = 32; off > 0; off >>= 1) q += __shfl_down(q, off);
  if ((t & 63) == 0) sm[t >> 6] = q;
  __syncthreads();
  float var = (sm[0] + sm[1] + sm[2] + sm[3]) * (1.f / DM);
  float rs = rsqrtf(var + 1e-5f);
  bf16_t* orow = o + (long)row * DM;
  orow[t]       = (bf16_t)(d0 * rs * g[t]       + bta[t]);
  orow[t + 256] = (bf16_t)(d1 * rs * g[t + 256] + bta[t + 256]);
  orow[t + 512] = (bf16_t)(d2 * rs * g[t + 512] + bta[t + 512]);
}

__device__ __forceinline__ void stage16(const bf16_t* gp, bf16_t* lp) {
  __builtin_amdgcn_global_load_lds(
      (const __attribute__((address_space(1))) uint32_t*)gp,
      (__attribute__((address_space(3))) uint32_t*)lp, 16, 0, 0);
}

#define WAITV8()  asm volatile("s_waitcnt vmcnt(8)" ::: "memory")
#define WAITV0()  asm volatile("s_waitcnt vmcnt(0)" ::: "memory")
#define BARRIER() do { __builtin_amdgcn_s_barrier();                            \
                       asm volatile("" ::: "memory"); } while (0)

// ====== 256^2 BK=64 double-buffered GEMM, hoisted-operand compute (R8/R11 best) ======
#define GLD256(ab, j, ktt, pp) do {                                             \
    int idx_ = (j) * 512 + tid;                                                 \
    int r_ = idx_ >> 3; int c16_ = idx_ & 7;                                    \
    size_t col_ = (size_t)(ktt) * 64 + (size_t)((c16_ ^ (r_ & 7)) << 3);        \
    const bf16_t* gp_ = (ab) ? (Wp + ((size_t)(n0 + r_)) * K + col_)            \
                             : (Ap + ((size_t)(m0 + r_)) * K + col_);           \
    bf16_t* lp_ = lds + ((((pp) * 2 + (ab)) * 256 + r_) * 64) + c16_ * 8;       \
    stage16(gp_, lp_);                                                          \
  } while (0)

#define STAGE256(pp, ktt) do {                                                  \
    GLD256(0, 0, ktt, pp); GLD256(0, 1, ktt, pp);                               \
    GLD256(0, 2, ktt, pp); GLD256(0, 3, ktt, pp);                               \
    GLD256(1, 0, ktt, pp); GLD256(1, 1, ktt, pp);                               \
    GLD256(1, 2, ktt, pp); GLD256(1, 3, ktt, pp);                               \
  } while (0)

#define COMPUTE_KH(pp, kh) do {                                                 \
    const char* lb_ = (const char*)lds;                                         \
    bf16x8 bfr_[4];                                                             \
    _Pragma("unroll") for (int f = 0; f < 4; ++f) {                             \
      int row_ = wn * 64 + f * 16 + fr;                                         \
      int byte_ = (((pp) * 2 + 1) * 256 + row_) * 128 +                         \
                  (((kh) * 64 + kq * 16) ^ ((row_ & 7) << 4));                  \
      bfr_[f] = *(const bf16x8*)(lb_ + byte_);                                  \
    }                                                                           \
    _Pragma("unroll") for (int mg = 0; mg < 2; ++mg) {                          \
      bf16x8 afr_[4];                                                           \
      _Pragma("unroll") for (int f = 0; f < 4; ++f) {                           \
        int row_ = wm * 128 + mg * 64 + f * 16 + fr;                            \
        int byte_ = (((pp) * 2 + 0) * 256 + row_) * 128 +                       \
                    (((kh) * 64 + kq * 16) ^ ((row_ & 7) << 4));                \
        afr_[f] = *(const bf16x8*)(lb_ + byte_);                                \
      }                                                                         \
      __builtin_amdgcn_s_setprio(1);                                            \
      _Pragma("unroll") for (int fm = 0; fm < 4; ++fm)                          \
        _Pragma("unroll") for (int fn = 0; fn < 4; ++fn)                        \
          acc[mg * 4 + fm][fn] = __builtin_amdgcn_mfma_f32_16x16x32_bf16(       \
              afr_[fm], bfr_[fn], acc[mg * 4 + fm][fn], 0, 0, 0);               \
      __builtin_amdgcn_s_setprio(0);                                            \
    }                                                                           \
  } while (0)

// EPI: 0 plain f32 full-line | 1 bias + nontemporal f32 | 2 bf16-only side
template <int EPI>
__global__ __launch_bounds__(512, 2) void k_gemm256(const bf16_t* __restrict__ Ap,
                                                    const bf16_t* __restrict__ Wp,
                                                    float* __restrict__ C,
                                                    const float* __restrict__ bias,
                                                    bf16_t* __restrict__ side,
                                                    int K, int ldc) {
  __shared__ bf16_t lds[2 * 2 * 256 * 64];   // 128 KiB: [buf][A|B][256][64]
  const int tid = threadIdx.x;
  const int lane = tid & 63;
  const int wid = tid >> 6;
  const int wm = wid >> 2, wn = wid & 3;
  const int fr = lane & 15, kq = lane >> 4;

  const int cpx = gridDim.x >> 3;
  const int wg = ((int)blockIdx.x & 7) * cpx + ((int)blockIdx.x >> 3);
  const long m0 = (long)(wg & 15) * 256;
  const long n0 = (long)(wg >> 4) * 256;

  f32x4 acc[8][4];
#pragma unroll
  for (int i = 0; i < 8; i++)
#pragma unroll
    for (int j = 0; j < 4; j++) acc[i][j] = (f32x4){0.f, 0.f, 0.f, 0.f};

  STAGE256(0, 0);
  const int NT = K >> 6;
  for (int kt = 0; kt < NT; ++kt) {
    const int p = kt & 1;
    const bool pre = (kt + 1 < NT);
    if (pre) STAGE256(p ^ 1, kt + 1);
    if (pre) WAITV8(); else WAITV0();
    BARRIER();
    COMPUTE_KH(p, 0);
    COMPUTE_KH(p, 1);
    BARRIER();
  }

  // ---- LDS-transposed epilogue: full-line stores (260-pad) ----
  {
    float* lf = (float*)(void*)lds;
    const int q = lane >> 4;
    const int cc = lane & 15;
    float4 bias4 = {0.f, 0.f, 0.f, 0.f};
    if (EPI == 1) bias4 = *(const float4*)&bias[n0 + lane * 4];
#pragma unroll
    for (int p = 0; p < 4; ++p) {
      __syncthreads();
      if (wm == (p >> 1)) {
        const int mgb = (p & 1) * 4;
#pragma unroll
        for (int m4 = 0; m4 < 4; ++m4)
#pragma unroll
          for (int n = 0; n < 4; ++n) {
            f32x4 v = acc[mgb + m4][n];
            float* dst = &lf[(m4 * 16 + q * 4) * 260 + wn * 64 + n * 16 + cc];
#pragma unroll
            for (int r = 0; r < 4; ++r) dst[r * 260] = v[r];
          }
      }
      __syncthreads();
      const long rowg0 = m0 + p * 64;
#pragma unroll
      for (int it = 0; it < 8; ++it) {
        int row_loc = wid * 8 + it;
        f32x4 v = *(const f32x4*)&lf[row_loc * 260 + lane * 4];
        long row = rowg0 + row_loc;
        long cg = n0 + lane * 4;
        if (EPI == 1) {
          v[0] += bias4.x; v[1] += bias4.y; v[2] += bias4.z; v[3] += bias4.w;
          __builtin_nontemporal_store(v, (f32x4*)&C[row * (long)ldc + cg]);
        } else if (EPI == 2) {
          bf16x4 s4;
          s4[0] = (bf16_t)v[0]; s4[1] = (bf16_t)v[1];
          s4[2] = (bf16_t)v[2]; s4[3] = (bf16_t)v[3];
          *(bf16x4*)&side[row * (long)ldc + cg] = s4;
        } else {
          *(f32x4*)&C[row * (long)ldc + cg] = v;
        }
      }
    }
  }
}

// ====== 128^2 BK=64 double-buffered GEMM, 2 blocks/CU (R8-proven) ======
// EPI: 4 softplus(acc+bias)->bf16 side | 5 += C + bf16 side | 7 K-slice partial
#define WAITV8B() asm volatile("s_waitcnt vmcnt(8)" ::: "memory")

#define GLD128(ab, j, ktt, pp) do {                                             \
    int idx_ = (j) * 256 + tid;                                                 \
    int r_ = idx_ >> 3; int c16_ = idx_ & 7;                                    \
    size_t col_ = kb + (size_t)(ktt) * 64 + (size_t)((c16_ ^ (r_ & 7)) << 3);   \
    const bf16_t* gp_ = (ab) ? (Wp + ((size_t)(n0 + r_)) * K + col_)            \
                             : (Ap + ((size_t)(m0 + r_)) * K + col_);           \
    bf16_t* lp_ = lds + ((((pp) * 2 + (ab)) * 128 + r_) * 64) + c16_ * 8;       \
    stage16(gp_, lp_);                                                          \
  } while (0)

#define STAGE128(pp, ktt) do {                                                  \
    GLD128(0, 0, ktt, pp); GLD128(0, 1, ktt, pp);                               \
    GLD128(0, 2, ktt, pp); GLD128(0, 3, ktt, pp);                               \
    GLD128(1, 0, ktt, pp); GLD128(1, 1, ktt, pp);                               \
    GLD128(1, 2, ktt, pp); GLD128(1, 3, ktt, pp);                               \
  } while (0)

#define COMPUTE128(pp, kh) do {                                                 \
    const char* lb_ = (const char*)lds;                                         \
    bf16x8 af_[4], bv_[4];                                                      \
    _Pragma("unroll") for (int f = 0; f < 4; ++f) {                             \
      int row_ = wn * 64 + f * 16 + fr;                                         \
      int byte_ = (((pp) * 2 + 1) * 128 + row_) * 128 +                         \
                  (((kh) * 64 + kq * 16) ^ ((row_ & 7) << 4));                  \
      bv_[f] = *(const bf16x8*)(lb_ + byte_);                                   \
    }                                                                           \
    _Pragma("unroll") for (int f = 0; f < 4; ++f) {                             \
      int row_ = wm * 64 + f * 16 + fr;                                         \
      int byte_ = (((pp) * 2 + 0) * 128 + row_) * 128 +                         \
                  (((kh) * 64 + kq * 16) ^ ((row_ & 7) << 4));                  \
      af_[f] = *(const bf16x8*)(lb_ + byte_);                                   \
    }                                                                           \
    __builtin_amdgcn_s_setprio(1);                                              \
    _Pragma("unroll") for (int fm = 0; fm < 4; ++fm)                            \
      _Pragma("unroll") for (int fn = 0; fn < 4; ++fn)                          \
        acc[fm][fn] = __builtin_amdgcn_mfma_f32_16x16x32_bf16(                  \
            af_[fm], bv_[fn], acc[fm][fn], 0, 0, 0);                            \
    __builtin_amdgcn_s_setprio(0);                                              \
  } while (0)

template <int EPI>
__global__ __launch_bounds__(256, 2) void k_gemm128(const bf16_t* __restrict__ Ap,
                                                    const bf16_t* __restrict__ Wp,
                                                    float* __restrict__ C,
                                                    const float* __restrict__ bias,
                                                    bf16_t* __restrict__ side,
                                                    int K, int Ksl, int ldc) {
  __shared__ bf16_t lds[2 * 2 * 128 * 64];   // 64 KiB
  const int tid = threadIdx.x;
  const int lane = tid & 63;
  const int wv = tid >> 6;
  const int wm = wv >> 1, wn = wv & 1;
  const int fr = lane & 15, kq = lane >> 4;
  const size_t kb = (size_t)blockIdx.y * Ksl;

  const int cpx = gridDim.x >> 3;
  const int wg = ((int)blockIdx.x & 7) * cpx + ((int)blockIdx.x >> 3);
  const long m0 = (long)(wg & 31) * 128;
  const long n0 = (long)(wg >> 5) * 128;

  f32x4 acc[4][4];
#pragma unroll
  for (int i = 0; i < 4; i++)
#pragma unroll
    for (int j = 0; j < 4; j++) acc[i][j] = (f32x4){0.f, 0.f, 0.f, 0.f};

  STAGE128(0, 0);
  const int NT = Ksl >> 6;
  for (int kt = 0; kt < NT; ++kt) {
    const int p = kt & 1;
    const bool pre = (kt + 1 < NT);
    if (pre) STAGE128(p ^ 1, kt + 1);
    if (pre) WAITV8B(); else WAITV0();
    BARRIER();
    COMPUTE128(p, 0);
    COMPUTE128(p, 1);
    BARRIER();
  }

  if (EPI == 7) {
    float* Cs = C + (size_t)blockIdx.y * (size_t)BL * 80;
    const int r4 = (lane >> 4) * 4;
    const int cc = lane & 15;
#pragma unroll
    for (int fm = 0; fm < 4; fm++) {
      long rowb = m0 + wm * 64 + fm * 16 + r4;
#pragma unroll
      for (int fn = 0; fn < 4; fn++) {
        long col = n0 + wn * 64 + fn * 16 + cc;
        if (col < 80) {
#pragma unroll
          for (int r = 0; r < 4; r++)
            Cs[(rowb + r) * 80 + col] = acc[fm][fn][r];
        }
      }
    }
    return;
  }

  // ---- full-line epilogue: 32-row chunks in LDS (132-f32 pad) ----
  {
    float* lf = (float*)(void*)lds;    // 32 x 132 f32 = 16.9 KB
    const int q = lane >> 4;
    const int cc = lane & 15;
    const int colt = (tid & 31) * 4;
    float4 bias4 = {0.f, 0.f, 0.f, 0.f};
    if (EPI == 4) bias4 = *(const float4*)&bias[n0 + colt];
#pragma unroll
    for (int p = 0; p < 4; ++p) {
      __syncthreads();
      if (wm == (p >> 1)) {
#pragma unroll
        for (int fl = 0; fl < 2; ++fl) {
          int fm = (p & 1) * 2 + fl;
#pragma unroll
          for (int fn = 0; fn < 4; ++fn) {
            f32x4 v = acc[fm][fn];
            float* dst = &lf[(fl * 16 + q * 4) * 132 + wn * 64 + fn * 16 + cc];
#pragma unroll
            for (int r = 0; r < 4; ++r) dst[r * 132] = v[r];
          }
        }
      }
      __syncthreads();
      const long rowg0 = m0 + p * 32;
#pragma unroll
      for (int it = 0; it < 4; ++it) {
        int rl = it * 8 + (tid >> 5);
        f32x4 v = *(const f32x4*)&lf[rl * 132 + colt];
        long row = rowg0 + rl;
        long cg = n0 + colt;
        if (EPI == 4) {
          bf16x4 s4;
          s4[0] = (bf16_t)softplus_(v[0] + bias4.x);
          s4[1] = (bf16_t)softplus_(v[1] + bias4.y);
          s4[2] = (bf16_t)softplus_(v[2] + bias4.z);
          s4[3] = (bf16_t)softplus_(v[3] + bias4.w);
          *(bf16x4*)&side[row * (long)ldc + cg] = s4;
        } else {  // EPI == 5: residual + bf16 side copy
          float* gp = &C[row * (long)ldc + cg];
          f32x4 c0 = *(const f32x4*)gp;
          v[0] += c0[0]; v[1] += c0[1]; v[2] += c0[2]; v[3] += c0[3];
          *(f32x4*)gp = v;
          bf16x4 s4;
          s4[0] = (bf16_t)v[0]; s4[1] = (bf16_t)v[1];
          s4[2] = (bf16_t)v[2]; s4[3] = (bf16_t)v[3];
          *(bf16x4*)&side[row * (long)ldc + cg] = s4;
        }
      }
    }
  }
}

static inline int cdiv_l(long a, long b) { return (int)((a + b - 1) / b); }

extern "C" void kernel_launch(void* const* d_in, const int* in_sizes, int n_in,
                              void* d_out, int out_size, void* d_ws, size_t ws_size,
                              hipStream_t stream) {
  (void)in_sizes; (void)n_in; (void)out_size; (void)ws_size;
  const int*   x      = (const int*)  d_in[0];
  const float* emb    = (const float*)d_in[1];
  const float* W_in   = (const float*)d_in[2];
  const float* conv_w = (const float*)d_in[3];
  const float* conv_b = (const float*)d_in[4];
  const float* W_x    = (const float*)d_in[5];
  const float* W_dt   = (const float*)d_in[6];
  const float* b_dt   = (const float*)d_in[7];
  const float* A_log  = (const float*)d_in[8];
  const float* D_skip = (const float*)d_in[9];
  const float* W_out  = (const float*)d_in[10];
  const float* ln_g   = (const float*)d_in[11];
  const float* ln_b   = (const float*)d_in[12];
  const float* head_w = (const float*)d_in[13];
  const float* head_b = (const float*)d_in[14];
  float* out = (float*)d_out;

  // bf16 staging in d_ws (~84 MB)
  bf16_t* abuf   = (bf16_t*)d_ws;                       // BL*DI (u, then y in-place)
  bf16_t* hbf    = abuf   + (size_t)BL * DI;            // BL*DM
  bf16_t* dtl    = hbf    + (size_t)BL * DM;            // BL*64
  bf16_t* wb_in  = dtl    + (size_t)BL * 64;            // 2*3072*768
  bf16_t* wb_out = wb_in  + (size_t)2 * 3072 * 768;     // 2*768*1536
  bf16_t* wb_hd  = wb_out + (size_t)2 * 768 * 1536;     // 32000*768
  bf16_t* wb_x   = wb_hd  + (size_t)VOC * DM;           // 2*128*1536
  bf16_t* wb_dt  = wb_x   + (size_t)2 * 128 * 1536;     // 2*1536*64

  // intermediates overlaid into d_out (all dead before head GEMM)
  bf16_t* xzb   = (bf16_t*)out;                         // BL*2DI bf16 (in f32-sized slot)
  float*  xdbl  = out   + (size_t)BL * 2 * DI;
  float*  dtb_f = xdbl  + (size_t)BL * 80;              // region reused as bf16
  bf16_t* dtbb  = (bf16_t*)dtb_f;                       // BL*DI bf16
  float*  h     = dtb_f + (size_t)BL * DI;
  float*  cA    = h     + (size_t)BL * DM;
  float*  cB    = cA    + (size_t)BATCH * NCH * DI * DS;
  float*  hst   = cB    + (size_t)BATCH * NCH * DI * DS;
  float*  xpart = hst   + (size_t)BATCH * DI * DS;      // 4 * BL * 80

  const int scan_blocks = BATCH * NCH * DI * DS / 256;  // 6144
  const int st_blocks   = BATCH * DI * DS / 256;        // 192

  // all weight conversions in one pass (independent of activations)
  k_cvtw<<<cdiv_l(NTOT, 256), 256, 0, stream>>>(W_in, W_out, head_w, W_x, W_dt,
                                                wb_in, wb_out, wb_hd, wb_x, wb_dt);
  k_embed<<<BL, 256, 0, stream>>>(x, emb, h, hbf, dtl);

  for (int l = 0; l < NL; ++l) {
    // ---- in_proj: xz(bf16) = h @ W_in^T  (4096 x 3072, K=768): 256^2 hoisted ----
    k_gemm256<2><<<(BL / 256) * (2 * DI / 256), 512, 0, stream>>>(
        hbf, wb_in + (size_t)l * 3072 * 768, nullptr, nullptr, xzb, DM, 2 * DI);
    // ---- causal dw-conv + silu -> bf16 u (abuf) ----
    k_conv<<<cdiv_l((long)BL * DI, 256), 256, 0, stream>>>(
        xzb, conv_w + (size_t)l * DI * DCONV, conv_b + (size_t)l * DI,
        abuf, (long)BL * DI);
    // ---- x_proj: 4 K-slice partials (no atomics) then finisher ----
    k_gemm128<7><<<dim3(32, 4), 256, 0, stream>>>(
        abuf, wb_x + (size_t)l * 128 * 1536, xpart, nullptr, nullptr,
        DI, DI / 4, 80);
    k_xfin<<<cdiv_l((long)BL * 80, 256), 256, 0, stream>>>(xpart, xdbl, dtl);
    // ---- dt = softplus(dtlin @ W_dt^T + b_dt) -> bf16 (K=64, NT=1) ----
    k_gemm128<4><<<(BL / 128) * (DI / 128), 256, 0, stream>>>(
        dtl, wb_dt + (size_t)l * 1536 * 64, nullptr, b_dt + (size_t)l * DI, dtbb,
        64, 64, DI);
    // ---- chunked selective scan (pass 3 fused with skip+gate, y in-place) ----
    k_scan1<<<scan_blocks, 256, 0, stream>>>(dtbb, abuf, xdbl,
                                             A_log + (size_t)l * DI * DS, cA, cB);
    k_scan2<<<st_blocks, 256, 0, stream>>>(cA, cB, hst);
    k_scan3g<<<scan_blocks, 256, 0, stream>>>(dtbb, abuf, xdbl,
                                              A_log + (size_t)l * DI * DS, hst,
                                              xzb, D_skip + (size_t)l * DI, abuf);
    // ---- out_proj + residual: h += y @ W_out^T (K=1536) ----
    k_gemm128<5><<<(BL / 128) * (DM / 128), 256, 0, stream>>>(
        abuf, wb_out + (size_t)l * 768 * 1536, h, nullptr, hbf, DI, DI, DM);
  }

  // ---- final LN -> bf16, head GEMM + bias: 256^2 hoisted, nt full-line ----
  k_ln<<<BL, 256, 0, stream>>>(h, ln_g, ln_b, abuf);
  k_gemm256<1><<<(BL / 256) * (VOC / 256), 512, 0, stream>>>(
      abuf, wb_hd, out, head_b, nullptr, DM, VOC);
}

// Round 14
// 948.499 us; speedup vs baseline: 1.0712x; 1.0049x over previous
//
#include <hip/hip_runtime.h>
#include <hip/hip_bf16.h>
#include <stdint.h>

#define BL    4096      // BATCH*SEQ
#define DM    768       // d_model
#define DI    1536      // d_inner
#define DS    16        // d_state
#define DCONV 4
#define DTR   48        // dt_rank
#define NL    2
#define SEQL  2048
#define BATCH 2
#define VOC   32000
#define NCH   32        // scan chunks
#define CT    64        // steps per chunk (SEQL/NCH)

typedef __bf16 bf16_t;
typedef __bf16 bf16x8 __attribute__((ext_vector_type(8)));
typedef __bf16 bf16x4 __attribute__((ext_vector_type(4)));
typedef float  f32x4  __attribute__((ext_vector_type(4)));

__device__ __forceinline__ float sigmoidf_(float x) { return 1.f / (1.f + __expf(-x)); }
__device__ __forceinline__ float softplus_(float x) {
  return (x > 20.f) ? x : log1pf(__expf(x));
}

// ------- embedding gather -> bf16 residual; also one-time dtl pad-zero -------
__global__ __launch_bounds__(256) void k_embed(const int* __restrict__ x,
                                               const float* __restrict__ emb,
                                               bf16_t* __restrict__ hb,
                                               bf16_t* __restrict__ dtl) {
  int row = blockIdx.x;
  if (row < 256) {   // zero dtl cols 48..63 for rows row*16..row*16+15 (once)
    int r = row * 16 + (threadIdx.x >> 4);
    dtl[r * 64 + 48 + (threadIdx.x & 15)] = (bf16_t)0.f;
  }
  int tok = x[row];
  const float* e = emb + (size_t)tok * DM;
  bf16_t* hbr = hb + (size_t)row * DM;
  for (int c = threadIdx.x; c < DM; c += 256)
    hbr[c] = (bf16_t)e[c];
}

// ------------- batched weight conversion: ALL weights f32->bf16 in one pass -------------
#define NV0 1179648L   // W_in  (2*3072*768)/4
#define NV1 589824L    // W_out (2*768*1536)/4
#define NV2 6144000L   // head  (32000*768)/4
#define NS3 393216L    // W_x padded elems 2*128*1536
#define NS4 196608L    // W_dt padded elems 2*1536*64
#define NVT (NV0 + NV1 + NV2)
#define NTOT (NVT + NS3 + NS4)

__global__ __launch_bounds__(256) void k_cvtw(const float* __restrict__ Win,
                                              const float* __restrict__ Wout,
                                              const float* __restrict__ Whead,
                                              const float* __restrict__ Wx,
                                              const float* __restrict__ Wdt,
                                              bf16_t* __restrict__ bin,
                                              bf16_t* __restrict__ bout,
                                              bf16_t* __restrict__ bhead,
                                              bf16_t* __restrict__ bx,
                                              bf16_t* __restrict__ bdt) {
  long i = (long)blockIdx.x * 256 + threadIdx.x;
  if (i >= NTOT) return;
  if (i < NVT) {
    const float* s; bf16_t* d; long j = i;
    if (i < NV0)            { s = Win;   d = bin; }
    else if (i < NV0 + NV1) { s = Wout;  d = bout;  j = i - NV0; }
    else                    { s = Whead; d = bhead; j = i - NV0 - NV1; }
    float4 v = ((const float4*)s)[j];
    bf16x4 o;
    o[0] = (bf16_t)v.x; o[1] = (bf16_t)v.y; o[2] = (bf16_t)v.z; o[3] = (bf16_t)v.w;
    ((bf16x4*)d)[j] = o;
  } else if (i < NVT + NS3) {
    long j = i - NVT;                       // [l][128][1536]
    int l = (int)(j / (128 * 1536));
    int rr = (int)((j / 1536) % 128);
    int c = (int)(j % 1536);
    bx[j] = (bf16_t)(rr < 80 ? Wx[((long)l * 80 + rr) * 1536 + c] : 0.f);
  } else {
    long j = i - NVT - NS3;                 // [l][1536][64]
    int l = (int)(j / (1536 * 64));
    int r = (int)((j / 64) % 1536);
    int c = (int)(j & 63);
    bdt[j] = (bf16_t)(c < DTR ? Wdt[((long)l * 1536 + r) * DTR + c] : 0.f);
  }
}

// ------------- causal dw-conv + bias + silu -> bf16 (xz bf16) -------------
__global__ __launch_bounds__(256) void k_conv(const bf16_t* __restrict__ xz,
                                              const float* __restrict__ cw,
                                              const float* __restrict__ cb,
                                              bf16_t* __restrict__ ucb, long total) {
  long i = (long)blockIdx.x * 256 + threadIdx.x;
  if (i >= total) return;
  int d = (int)(i % DI);
  long row = i / DI;
  int l = (int)(row % SEQL);
  const float* w = cw + (size_t)d * DCONV;
  float s = cb[d];
#pragma unroll
  for (int j = 0; j < DCONV; j++) {
    int lj = l - (DCONV - 1) + j;
    if (lj >= 0) s += (float)xz[(row - (DCONV - 1) + j) * (2 * DI) + d] * w[j];
  }
  float v = s * sigmoidf_(s);
  ucb[i] = (bf16_t)v;
}

// ------------- x_proj finisher: sum 4 K-slices, emit xdbl f32 + dt-input bf16 -------------
__global__ __launch_bounds__(256) void k_xfin(const float* __restrict__ xp,
                                              float* __restrict__ xdbl,
                                              bf16_t* __restrict__ dtl) {
  long i = (long)blockIdx.x * 256 + threadIdx.x;
  if (i >= (long)BL * 80) return;
  float s = xp[i] + xp[i + (long)BL * 80] + xp[i + 2L * BL * 80] + xp[i + 3L * BL * 80];
  xdbl[i] = s;
  int row = (int)(i / 80), col = (int)(i % 80);
  if (col < DTR) dtl[(long)row * 64 + col] = (bf16_t)s;
}

// ============ chunked selective scan (u and dt read as bf16) ============
__global__ __launch_bounds__(256) void k_scan1(const bf16_t* __restrict__ dt,
                                               const bf16_t* __restrict__ uc,
                                               const float* __restrict__ xdbl,
                                               const float* __restrict__ A_log,
                                               float* __restrict__ cA,
                                               float* __restrict__ cB) {
  int gi = blockIdx.x * 256 + threadIdx.x;
  int s = gi & 15;
  int rest = gi >> 4;          // [b][c][d]
  int d = rest % DI;
  int rest2 = rest / DI;
  int c = rest2 % NCH;
  int b = rest2 / NCH;
  float a = -__expf(A_log[d * DS + s]);
  long l0 = (long)c * CT;
  const bf16_t* dtp = dt + ((long)b * SEQL + l0) * DI + d;
  const bf16_t* ucp = uc + ((long)b * SEQL + l0) * DI + d;
  const float*  Bp  = xdbl + ((long)b * SEQL + l0) * 80 + DTR + s;
  float S = 0.f, hh = 0.f;
#pragma unroll 4
  for (int l = 0; l < CT; l++) {
    float dtv = (float)dtp[(long)l * DI];
    float uv  = (float)ucp[(long)l * DI];
    float Bv  = Bp[(long)l * 80];
    S += dtv;
    hh = __expf(dtv * a) * hh + (dtv * uv) * Bv;
  }
  cA[gi] = __expf(a * S);
  cB[gi] = hh;
}

__global__ __launch_bounds__(256) void k_scan2(const float* __restrict__ cA,
                                               const float* __restrict__ cB,
                                               float* __restrict__ hst) {
  int gj = blockIdx.x * 256 + threadIdx.x;   // [b][d][s]
  int ds_ = gj & (DI * DS - 1);
  int b = gj / (DI * DS);
  float h = 0.f;
#pragma unroll
  for (int c = 0; c < NCH; c++) {
    long idx = ((long)(b * NCH + c) * DI * DS) + ds_;
    hst[idx] = h;
    h = cA[idx] * h + cB[idx];
  }
}

// ---- pass 3 + skip + gate fused. o aliases uc (in-place y over u): each (l,d)
// element is read by all 16 lanes before the s==0 lane writes it.
__global__ __launch_bounds__(256) void k_scan3g(const bf16_t* __restrict__ dt,
                                                const bf16_t* uc,
                                                const float* __restrict__ xdbl,
                                                const float* __restrict__ A_log,
                                                const float* __restrict__ hst,
                                                const bf16_t* __restrict__ xz,
                                                const float* __restrict__ Dsk,
                                                bf16_t* o) {
  int gi = blockIdx.x * 256 + threadIdx.x;
  int s = gi & 15;
  int rest = gi >> 4;
  int d = rest % DI;
  int rest2 = rest / DI;
  int c = rest2 % NCH;
  int b = rest2 / NCH;
  float a = -__expf(A_log[d * DS + s]);
  float dval = Dsk[d];
  long l0 = (long)c * CT;
  const bf16_t* dtp = dt + ((long)b * SEQL + l0) * DI + d;
  const bf16_t* ucp = uc + ((long)b * SEQL + l0) * DI + d;
  const float*  Bp  = xdbl + ((long)b * SEQL + l0) * 80 + DTR + s;
  const float*  Cp  = Bp + DS;
  const bf16_t* zp  = xz + ((long)b * SEQL + l0) * (2 * DI) + DI + d;
  bf16_t* yp = o + ((long)b * SEQL + l0) * DI + d;
  float h = hst[gi];
#pragma unroll 4
  for (int l = 0; l < CT; l++) {
    float dtv = (float)dtp[(long)l * DI];
    float uv  = (float)ucp[(long)l * DI];
    float Bv  = Bp[(long)l * 80];
    float Cv  = Cp[(long)l * 80];
    h = __expf(dtv * a) * h + (dtv * uv) * Bv;
    float y = h * Cv;
    y += __shfl_xor(y, 1);
    y += __shfl_xor(y, 2);
    y += __shfl_xor(y, 4);
    y += __shfl_xor(y, 8);
    if (s == 0) {
      float z = (float)zp[(long)l * 2 * DI];
      float yy = (y + uv * dval) * z * sigmoidf_(z);
      yp[(long)l * DI] = (bf16_t)yy;
    }
  }
}

// ---------------- final LayerNorm (bf16 in), write bf16 A-operand ----------------
__global__ __launch_bounds__(256) void k_ln(const bf16_t* __restrict__ h,
                                            const float* __restrict__ g,
                                            const float* __restrict__ bta,
                                            bf16_t* __restrict__ o) {
  __shared__ float sm[4];
  int row = blockIdx.x;
  int t = threadIdx.x;
  const bf16_t* hr = h + (long)row * DM;
  float v0 = (float)hr[t], v1 = (float)hr[t + 256], v2 = (float)hr[t + 512];
  float s = v0 + v1 + v2;
#pragma unroll
  for (int off = 32; off > 0; off >>= 1) s += __shfl_down(s, off);
  if ((t & 63) == 0) sm[t >> 6] = s;
  __syncthreads();
  float mu = (sm[0] + sm[1] + sm[2] + sm[3]) * (1.f / DM);
  __syncthreads();
  float d0 = v0 - mu, d1 = v1 - mu, d2 = v2 - mu;
  float q = d0 * d0 + d1 * d1 + d2 * d2;
#pragma unroll
  for (int off = 32; off > 0; off >>= 1) q += __shfl_down(q, off);
  if ((t & 63) == 0) sm[t >> 6] = q;
  __syncthreads();
  float var = (sm[0] + sm[1] + sm[2] + sm[3]) * (1.f / DM);
  float rs = rsqrtf(var + 1e-5f);
  bf16_t* orow = o + (long)row * DM;
  orow[t]       = (bf16_t)(d0 * rs * g[t]       + bta[t]);
  orow[t + 256] = (bf16_t)(d1 * rs * g[t + 256] + bta[t + 256]);
  orow[t + 512] = (bf16_t)(d2 * rs * g[t + 512] + bta[t + 512]);
}

__device__ __forceinline__ void stage16(const bf16_t* gp, bf16_t* lp) {
  __builtin_amdgcn_global_load_lds(
      (const __attribute__((address_space(1))) uint32_t*)gp,
      (__attribute__((address_space(3))) uint32_t*)lp, 16, 0, 0);
}

#define WAITV8()  asm volatile("s_waitcnt vmcnt(8)" ::: "memory")
#define WAITV0()  asm volatile("s_waitcnt vmcnt(0)" ::: "memory")
#define BARRIER() do { __builtin_amdgcn_s_barrier();                            \
                       asm volatile("" ::: "memory"); } while (0)

// ====== 256^2 BK=64 double-buffered GEMM, hoisted-operand compute (R8/R13 best) ======
#define GLD256(ab, j, ktt, pp) do {                                             \
    int idx_ = (j) * 512 + tid;                                                 \
    int r_ = idx_ >> 3; int c16_ = idx_ & 7;                                    \
    size_t col_ = (size_t)(ktt) * 64 + (size_t)((c16_ ^ (r_ & 7)) << 3);        \
    const bf16_t* gp_ = (ab) ? (Wp + ((size_t)(n0 + r_)) * K + col_)            \
                             : (Ap + ((size_t)(m0 + r_)) * K + col_);           \
    bf16_t* lp_ = lds + ((((pp) * 2 + (ab)) * 256 + r_) * 64) + c16_ * 8;       \
    stage16(gp_, lp_);                                                          \
  } while (0)

#define STAGE256(pp, ktt) do {                                                  \
    GLD256(0, 0, ktt, pp); GLD256(0, 1, ktt, pp);                               \
    GLD256(0, 2, ktt, pp); GLD256(0, 3, ktt, pp);                               \
    GLD256(1, 0, ktt, pp); GLD256(1, 1, ktt, pp);                               \
    GLD256(1, 2, ktt, pp); GLD256(1, 3, ktt, pp);                               \
  } while (0)

#define COMPUTE_KH(pp, kh) do {                                                 \
    const char* lb_ = (const char*)lds;                                         \
    bf16x8 bfr_[4];                                                             \
    _Pragma("unroll") for (int f = 0; f < 4; ++f) {                             \
      int row_ = wn * 64 + f * 16 + fr;                                         \
      int byte_ = (((pp) * 2 + 1) * 256 + row_) * 128 +                         \
                  (((kh) * 64 + kq * 16) ^ ((row_ & 7) << 4));                  \
      bfr_[f] = *(const bf16x8*)(lb_ + byte_);                                  \
    }                                                                           \
    _Pragma("unroll") for (int mg = 0; mg < 2; ++mg) {                          \
      bf16x8 afr_[4];                                                           \
      _Pragma("unroll") for (int f = 0; f < 4; ++f) {                           \
        int row_ = wm * 128 + mg * 64 + f * 16 + fr;                            \
        int byte_ = (((pp) * 2 + 0) * 256 + row_) * 128 +                       \
                    (((kh) * 64 + kq * 16) ^ ((row_ & 7) << 4));                \
        afr_[f] = *(const bf16x8*)(lb_ + byte_);                                \
      }                                                                         \
      __builtin_amdgcn_s_setprio(1);                                            \
      _Pragma("unroll") for (int fm = 0; fm < 4; ++fm)                          \
        _Pragma("unroll") for (int fn = 0; fn < 4; ++fn)                        \
          acc[mg * 4 + fm][fn] = __builtin_amdgcn_mfma_f32_16x16x32_bf16(       \
              afr_[fm], bfr_[fn], acc[mg * 4 + fm][fn], 0, 0, 0);               \
      __builtin_amdgcn_s_setprio(0);                                            \
    }                                                                           \
  } while (0)

// EPI: 1 bias + nontemporal f32 full-line | 2 bf16-only side
template <int EPI>
__global__ __launch_bounds__(512, 2) void k_gemm256(const bf16_t* __restrict__ Ap,
                                                    const bf16_t* __restrict__ Wp,
                                                    float* __restrict__ C,
                                                    const float* __restrict__ bias,
                                                    bf16_t* __restrict__ side,
                                                    int K, int ldc) {
  __shared__ bf16_t lds[2 * 2 * 256 * 64];   // 128 KiB: [buf][A|B][256][64]
  const int tid = threadIdx.x;
  const int lane = tid & 63;
  const int wid = tid >> 6;
  const int wm = wid >> 2, wn = wid & 3;
  const int fr = lane & 15, kq = lane >> 4;

  const int cpx = gridDim.x >> 3;
  const int wg = ((int)blockIdx.x & 7) * cpx + ((int)blockIdx.x >> 3);
  const long m0 = (long)(wg & 15) * 256;
  const long n0 = (long)(wg >> 4) * 256;

  f32x4 acc[8][4];
#pragma unroll
  for (int i = 0; i < 8; i++)
#pragma unroll
    for (int j = 0; j < 4; j++) acc[i][j] = (f32x4){0.f, 0.f, 0.f, 0.f};

  STAGE256(0, 0);
  const int NT = K >> 6;
  for (int kt = 0; kt < NT; ++kt) {
    const int p = kt & 1;
    const bool pre = (kt + 1 < NT);
    if (pre) STAGE256(p ^ 1, kt + 1);
    if (pre) WAITV8(); else WAITV0();
    BARRIER();
    COMPUTE_KH(p, 0);
    COMPUTE_KH(p, 1);
    BARRIER();
  }

  // ---- LDS-transposed epilogue: full-line stores (260-pad) ----
  {
    float* lf = (float*)(void*)lds;
    const int q = lane >> 4;
    const int cc = lane & 15;
    float4 bias4 = {0.f, 0.f, 0.f, 0.f};
    if (EPI == 1) bias4 = *(const float4*)&bias[n0 + lane * 4];
#pragma unroll
    for (int p = 0; p < 4; ++p) {
      __syncthreads();
      if (wm == (p >> 1)) {
        const int mgb = (p & 1) * 4;
#pragma unroll
        for (int m4 = 0; m4 < 4; ++m4)
#pragma unroll
          for (int n = 0; n < 4; ++n) {
            f32x4 v = acc[mgb + m4][n];
            float* dst = &lf[(m4 * 16 + q * 4) * 260 + wn * 64 + n * 16 + cc];
#pragma unroll
            for (int r = 0; r < 4; ++r) dst[r * 260] = v[r];
          }
      }
      __syncthreads();
      const long rowg0 = m0 + p * 64;
#pragma unroll
      for (int it = 0; it < 8; ++it) {
        int row_loc = wid * 8 + it;
        f32x4 v = *(const f32x4*)&lf[row_loc * 260 + lane * 4];
        long row = rowg0 + row_loc;
        long cg = n0 + lane * 4;
        if (EPI == 1) {
          v[0] += bias4.x; v[1] += bias4.y; v[2] += bias4.z; v[3] += bias4.w;
          __builtin_nontemporal_store(v, (f32x4*)&C[row * (long)ldc + cg]);
        } else {  // EPI == 2
          bf16x4 s4;
          s4[0] = (bf16_t)v[0]; s4[1] = (bf16_t)v[1];
          s4[2] = (bf16_t)v[2]; s4[3] = (bf16_t)v[3];
          *(bf16x4*)&side[row * (long)ldc + cg] = s4;
        }
      }
    }
  }
}

// ====== 128^2 BK=64 double-buffered GEMM, 2 blocks/CU (R8-proven) ======
// EPI: 4 softplus(acc+bias)->bf16 side | 7 K-slice partial | 8 bf16 residual RMW
#define WAITV8B() asm volatile("s_waitcnt vmcnt(8)" ::: "memory")

#define GLD128(ab, j, ktt, pp) do {                                             \
    int idx_ = (j) * 256 + tid;                                                 \
    int r_ = idx_ >> 3; int c16_ = idx_ & 7;                                    \
    size_t col_ = kb + (size_t)(ktt) * 64 + (size_t)((c16_ ^ (r_ & 7)) << 3);   \
    const bf16_t* gp_ = (ab) ? (Wp + ((size_t)(n0 + r_)) * K + col_)            \
                             : (Ap + ((size_t)(m0 + r_)) * K + col_);           \
    bf16_t* lp_ = lds + ((((pp) * 2 + (ab)) * 128 + r_) * 64) + c16_ * 8;       \
    stage16(gp_, lp_);                                                          \
  } while (0)

#define STAGE128(pp, ktt) do {                                                  \
    GLD128(0, 0, ktt, pp); GLD128(0, 1, ktt, pp);                               \
    GLD128(0, 2, ktt, pp); GLD128(0, 3, ktt, pp);                               \
    GLD128(1, 0, ktt, pp); GLD128(1, 1, ktt, pp);                               \
    GLD128(1, 2, ktt, pp); GLD128(1, 3, ktt, pp);                               \
  } while (0)

#define COMPUTE128(pp, kh) do {                                                 \
    const char* lb_ = (const char*)lds;                                         \
    bf16x8 af_[4], bv_[4];                                                      \
    _Pragma("unroll") for (int f = 0; f < 4; ++f) {                             \
      int row_ = wn * 64 + f * 16 + fr;                                         \
      int byte_ = (((pp) * 2 + 1) * 128 + row_) * 128 +                         \
                  (((kh) * 64 + kq * 16) ^ ((row_ & 7) << 4));                  \
      bv_[f] = *(const bf16x8*)(lb_ + byte_);                                   \
    }                                                                           \
    _Pragma("unroll") for (int f = 0; f < 4; ++f) {                             \
      int row_ = wm * 64 + f * 16 + fr;                                         \
      int byte_ = (((pp) * 2 + 0) * 128 + row_) * 128 +                         \
                  (((kh) * 64 + kq * 16) ^ ((row_ & 7) << 4));                  \
      af_[f] = *(const bf16x8*)(lb_ + byte_);                                   \
    }                                                                           \
    __builtin_amdgcn_s_setprio(1);                                              \
    _Pragma("unroll") for (int fm = 0; fm < 4; ++fm)                            \
      _Pragma("unroll") for (int fn = 0; fn < 4; ++fn)                          \
        acc[fm][fn] = __builtin_amdgcn_mfma_f32_16x16x32_bf16(                  \
            af_[fm], bv_[fn], acc[fm][fn], 0, 0, 0);                            \
    __builtin_amdgcn_s_setprio(0);                                              \
  } while (0)

template <int EPI>
__global__ __launch_bounds__(256, 2) void k_gemm128(const bf16_t* __restrict__ Ap,
                                                    const bf16_t* __restrict__ Wp,
                                                    float* __restrict__ C,
                                                    const float* __restrict__ bias,
                                                    bf16_t* __restrict__ side,
                                                    int K, int Ksl, int ldc) {
  __shared__ bf16_t lds[2 * 2 * 128 * 64];   // 64 KiB
  const int tid = threadIdx.x;
  const int lane = tid & 63;
  const int wv = tid >> 6;
  const int wm = wv >> 1, wn = wv & 1;
  const int fr = lane & 15, kq = lane >> 4;
  const size_t kb = (size_t)blockIdx.y * Ksl;

  const int cpx = gridDim.x >> 3;
  const int wg = ((int)blockIdx.x & 7) * cpx + ((int)blockIdx.x >> 3);
  const long m0 = (long)(wg & 31) * 128;
  const long n0 = (long)(wg >> 5) * 128;

  f32x4 acc[4][4];
#pragma unroll
  for (int i = 0; i < 4; i++)
#pragma unroll
    for (int j = 0; j < 4; j++) acc[i][j] = (f32x4){0.f, 0.f, 0.f, 0.f};

  STAGE128(0, 0);
  const int NT = Ksl >> 6;
  for (int kt = 0; kt < NT; ++kt) {
    const int p = kt & 1;
    const bool pre = (kt + 1 < NT);
    if (pre) STAGE128(p ^ 1, kt + 1);
    if (pre) WAITV8B(); else WAITV0();
    BARRIER();
    COMPUTE128(p, 0);
    COMPUTE128(p, 1);
    BARRIER();
  }

  if (EPI == 7) {
    float* Cs = C + (size_t)blockIdx.y * (size_t)BL * 80;
    const int r4 = (lane >> 4) * 4;
    const int cc = lane & 15;
#pragma unroll
    for (int fm = 0; fm < 4; fm++) {
      long rowb = m0 + wm * 64 + fm * 16 + r4;
#pragma unroll
      for (int fn = 0; fn < 4; fn++) {
        long col = n0 + wn * 64 + fn * 16 + cc;
        if (col < 80) {
#pragma unroll
          for (int r = 0; r < 4; r++)
            Cs[(rowb + r) * 80 + col] = acc[fm][fn][r];
        }
      }
    }
    return;
  }

  // ---- full-line epilogue: 32-row chunks in LDS (132-f32 pad) ----
  {
    float* lf = (float*)(void*)lds;    // 32 x 132 f32 = 16.9 KB
    const int q = lane >> 4;
    const int cc = lane & 15;
    const int colt = (tid & 31) * 4;
    float4 bias4 = {0.f, 0.f, 0.f, 0.f};
    if (EPI == 4) bias4 = *(const float4*)&bias[n0 + colt];
#pragma unroll
    for (int p = 0; p < 4; ++p) {
      __syncthreads();
      if (wm == (p >> 1)) {
#pragma unroll
        for (int fl = 0; fl < 2; ++fl) {
          int fm = (p & 1) * 2 + fl;
#pragma unroll
          for (int fn = 0; fn < 4; ++fn) {
            f32x4 v = acc[fm][fn];
            float* dst = &lf[(fl * 16 + q * 4) * 132 + wn * 64 + fn * 16 + cc];
#pragma unroll
            for (int r = 0; r < 4; ++r) dst[r * 132] = v[r];
          }
        }
      }
      __syncthreads();
      const long rowg0 = m0 + p * 32;
#pragma unroll
      for (int it = 0; it < 4; ++it) {
        int rl = it * 8 + (tid >> 5);
        f32x4 v = *(const f32x4*)&lf[rl * 132 + colt];
        long row = rowg0 + rl;
        long cg = n0 + colt;
        if (EPI == 4) {
          bf16x4 s4;
          s4[0] = (bf16_t)softplus_(v[0] + bias4.x);
          s4[1] = (bf16_t)softplus_(v[1] + bias4.y);
          s4[2] = (bf16_t)softplus_(v[2] + bias4.z);
          s4[3] = (bf16_t)softplus_(v[3] + bias4.w);
          *(bf16x4*)&side[row * (long)ldc + cg] = s4;
        } else {  // EPI == 8: bf16 residual read-modify-write (side in/out)
          bf16_t* sp = &side[row * (long)ldc + cg];
          bf16x4 c0 = *(const bf16x4*)sp;
          bf16x4 s4;
          s4[0] = (bf16_t)(v[0] + (float)c0[0]);
          s4[1] = (bf16_t)(v[1] + (float)c0[1]);
          s4[2] = (bf16_t)(v[2] + (float)c0[2]);
          s4[3] = (bf16_t)(v[3] + (float)c0[3]);
          *(bf16x4*)sp = s4;
        }
      }
    }
  }
}

static inline int cdiv_l(long a, long b) { return (int)((a + b - 1) / b); }

extern "C" void kernel_launch(void* const* d_in, const int* in_sizes, int n_in,
                              void* d_out, int out_size, void* d_ws, size_t ws_size,
                              hipStream_t stream) {
  (void)in_sizes; (void)n_in; (void)out_size; (void)ws_size;
  const int*   x      = (const int*)  d_in[0];
  const float* emb    = (const float*)d_in[1];
  const float* W_in   = (const float*)d_in[2];
  const float* conv_w = (const float*)d_in[3];
  const float* conv_b = (const float*)d_in[4];
  const float* W_x    = (const float*)d_in[5];
  const float* W_dt   = (const float*)d_in[6];
  const float* b_dt   = (const float*)d_in[7];
  const float* A_log  = (const float*)d_in[8];
  const float* D_skip = (const float*)d_in[9];
  const float* W_out  = (const float*)d_in[10];
  const float* ln_g   = (const float*)d_in[11];
  const float* ln_b   = (const float*)d_in[12];
  const float* head_w = (const float*)d_in[13];
  const float* head_b = (const float*)d_in[14];
  float* out = (float*)d_out;

  // bf16 staging in d_ws (~84 MB)
  bf16_t* abuf   = (bf16_t*)d_ws;                       // BL*DI (u, then y in-place)
  bf16_t* hbf    = abuf   + (size_t)BL * DI;            // BL*DM  (bf16 residual)
  bf16_t* dtl    = hbf    + (size_t)BL * DM;            // BL*64
  bf16_t* wb_in  = dtl    + (size_t)BL * 64;            // 2*3072*768
  bf16_t* wb_out = wb_in  + (size_t)2 * 3072 * 768;     // 2*768*1536
  bf16_t* wb_hd  = wb_out + (size_t)2 * 768 * 1536;     // 32000*768
  bf16_t* wb_x   = wb_hd  + (size_t)VOC * DM;           // 2*128*1536
  bf16_t* wb_dt  = wb_x   + (size_t)2 * 128 * 1536;     // 2*1536*64

  // intermediates overlaid into d_out (all dead before head GEMM writes out)
  bf16_t* xzb   = (bf16_t*)out;                         // BL*2DI bf16
  float*  xdbl  = out   + (size_t)BL * 2 * DI;          // BL*80 f32
  bf16_t* dtbb  = (bf16_t*)(xdbl + (size_t)BL * 80);    // BL*DI bf16 (in f32 slot)
  float*  cA    = xdbl  + (size_t)BL * 80 + (size_t)BL * DI;
  float*  cB    = cA    + (size_t)BATCH * NCH * DI * DS;
  float*  hst   = cB    + (size_t)BATCH * NCH * DI * DS;
  float*  xpart = hst   + (size_t)BATCH * NCH * DI * DS;  // 4 * BL * 80

  const int scan_blocks = BATCH * NCH * DI * DS / 256;  // 6144
  const int st_blocks   = BATCH * DI * DS / 256;        // 192

  // all weight conversions in one pass (independent of activations)
  k_cvtw<<<cdiv_l(NTOT, 256), 256, 0, stream>>>(W_in, W_out, head_w, W_x, W_dt,
                                                wb_in, wb_out, wb_hd, wb_x, wb_dt);
  k_embed<<<BL, 256, 0, stream>>>(x, emb, hbf, dtl);

  for (int l = 0; l < NL; ++l) {
    // ---- in_proj: xz(bf16) = h @ W_in^T  (4096 x 3072, K=768): 256^2 hoisted ----
    k_gemm256<2><<<(BL / 256) * (2 * DI / 256), 512, 0, stream>>>(
        hbf, wb_in + (size_t)l * 3072 * 768, nullptr, nullptr, xzb, DM, 2 * DI);
    // ---- causal dw-conv + silu -> bf16 u (abuf) ----
    k_conv<<<cdiv_l((long)BL * DI, 256), 256, 0, stream>>>(
        xzb, conv_w + (size_t)l * DI * DCONV, conv_b + (size_t)l * DI,
        abuf, (long)BL * DI);
    // ---- x_proj: 4 K-slice partials (no atomics) then finisher ----
    k_gemm128<7><<<dim3(32, 4), 256, 0, stream>>>(
        abuf, wb_x + (size_t)l * 128 * 1536, xpart, nullptr, nullptr,
        DI, DI / 4, 80);
    k_xfin<<<cdiv_l((long)BL * 80, 256), 256, 0, stream>>>(xpart, xdbl, dtl);
    // ---- dt = softplus(dtlin @ W_dt^T + b_dt) -> bf16 (K=64, NT=1) ----
    k_gemm128<4><<<(BL / 128) * (DI / 128), 256, 0, stream>>>(
        dtl, wb_dt + (size_t)l * 1536 * 64, nullptr, b_dt + (size_t)l * DI, dtbb,
        64, 64, DI);
    // ---- chunked selective scan (pass 3 fused with skip+gate, y in-place) ----
    k_scan1<<<scan_blocks, 256, 0, stream>>>(dtbb, abuf, xdbl,
                                             A_log + (size_t)l * DI * DS, cA, cB);
    k_scan2<<<st_blocks, 256, 0, stream>>>(cA, cB, hst);
    k_scan3g<<<scan_blocks, 256, 0, stream>>>(dtbb, abuf, xdbl,
                                              A_log + (size_t)l * DI * DS, hst,
                                              xzb, D_skip + (size_t)l * DI, abuf);
    // ---- out_proj + residual: hbf += y @ W_out^T (K=1536), bf16 RMW ----
    k_gemm128<8><<<(BL / 128) * (DM / 128), 256, 0, stream>>>(
        abuf, wb_out + (size_t)l * 768 * 1536, nullptr, nullptr, hbf, DI, DI, DM);
  }

  // ---- final LN (bf16 in) -> bf16, head GEMM + bias: 256^2, nt full-line ----
  k_ln<<<BL, 256, 0, stream>>>(hbf, ln_g, ln_b, abuf);
  k_gemm256<1><<<(BL / 256) * (VOC / 256), 512, 0, stream>>>(
      abuf, wb_hd, out, head_b, nullptr, DM, VOC);
}